// Round 13
// baseline (1462.640 us; speedup 1.0000x reference)
//
#include <hip/hip_runtime.h>

#define F_IN 128
#define HDIM 64
#define NUM_GRAPHS 256
#define SCAN_BLK 256
#define SCAN_CHUNK 2048   // 256 threads x 8 elems

// --- degree histogram (int): deg[dst] += 1 per edge ---
__global__ void hist_kernel(const int* __restrict__ dst, int* __restrict__ deg, int e) {
    int i = blockIdx.x * blockDim.x + threadIdx.x;
    if (i < e) atomicAdd(&deg[dst[i]], 1);
}

// --- scan pass A: per-block sums of deg over SCAN_CHUNK elems ---
__global__ void scan_partial(const int* __restrict__ deg, int* __restrict__ partial, int n) {
    __shared__ int lds[SCAN_BLK];
    int b = blockIdx.x, t = threadIdx.x;
    int base = b * SCAN_CHUNK + t * 8;
    int s = 0;
#pragma unroll
    for (int j = 0; j < 8; ++j) { int idx = base + j; if (idx < n) s += deg[idx]; }
    lds[t] = s; __syncthreads();
    for (int off = SCAN_BLK / 2; off; off >>= 1) {
        if (t < off) lds[t] += lds[t + off];
        __syncthreads();
    }
    if (t == 0) partial[b] = lds[0];
}

// --- scan pass B: serial exclusive scan of block sums (nb ~ 49) ---
__global__ void scan_spine(int* __restrict__ partial, int nb, int* __restrict__ off_end) {
    if (threadIdx.x == 0 && blockIdx.x == 0) {
        int run = 0;
        for (int i = 0; i < nb; ++i) { int v = partial[i]; partial[i] = run; run += v; }
        off_end[0] = run;
    }
}

// --- scan pass C: final exclusive scan; writes off[], cursor[], dinv[] ---
__global__ void scan_final(const int* __restrict__ deg, const int* __restrict__ partial,
                           int* __restrict__ off, int* __restrict__ cursor,
                           float* __restrict__ dinv, int n) {
    __shared__ int lds[SCAN_BLK];
    int b = blockIdx.x, t = threadIdx.x;
    int base = b * SCAN_CHUNK + t * 8;
    int v[8]; int s = 0;
#pragma unroll
    for (int j = 0; j < 8; ++j) { int idx = base + j; v[j] = (idx < n) ? deg[idx] : 0; s += v[j]; }
    lds[t] = s; __syncthreads();
    for (int o = 1; o < SCAN_BLK; o <<= 1) {
        int y = (t >= o) ? lds[t - o] : 0;
        __syncthreads();
        if (t >= o) lds[t] += y;
        __syncthreads();
    }
    int run = partial[b] + lds[t] - s;
#pragma unroll
    for (int j = 0; j < 8; ++j) {
        int idx = base + j;
        if (idx < n) {
            off[idx] = run; cursor[idx] = run;
            dinv[idx] = rsqrtf((float)v[j] + 1.0f);   // +1 self-loop
        }
        run += v[j];
    }
}

// --- CSR fill: csr[cursor[dst]++] = src ---
__global__ void fill_kernel(const int* __restrict__ src, const int* __restrict__ dst,
                            int* __restrict__ cursor, int* __restrict__ csr, int e) {
    int i = blockIdx.x * blockDim.x + threadIdx.x;
    if (i < e) {
        int pos = atomicAdd(&cursor[dst[i]], 1);
        csr[pos] = src[i];
    }
}

// --- small GEMM: out[n,64] = (A[n,K] @ W[K,64]) * dinv[row] ---
template<int K>
__global__ void gemm_kernel(const float* __restrict__ A, const float* __restrict__ W,
                            const float* __restrict__ dinv, float* __restrict__ out, int n) {
    __shared__ float Ws[K * 64];
    for (int i = threadIdx.x; i < K * 64; i += blockDim.x) Ws[i] = W[i];
    __syncthreads();
    int row  = blockIdx.x * (blockDim.x >> 6) + (threadIdx.x >> 6);
    int lane = threadIdx.x & 63;
    if (row >= n) return;
    const float4* ar = reinterpret_cast<const float4*>(A + (size_t)row * K);
    float acc = 0.f;
#pragma unroll
    for (int k4 = 0; k4 < K / 4; ++k4) {
        float4 av = ar[k4];
        acc = fmaf(av.x, Ws[(k4 * 4 + 0) * 64 + lane], acc);
        acc = fmaf(av.y, Ws[(k4 * 4 + 1) * 64 + lane], acc);
        acc = fmaf(av.z, Ws[(k4 * 4 + 2) * 64 + lane], acc);
        acc = fmaf(av.w, Ws[(k4 * 4 + 3) * 64 + lane], acc);
    }
    out[(size_t)row * 64 + lane] = acc * dinv[row];
}

// --- gather: one wave per dst node, lane = feature.
// Neighbor indices: one coalesced load per 64 edges, then readlane -> SGPR;
// row loads use scalar base + shared lane offset. 16 independent chains. ---
template<bool POOL>
__global__ void gather_kernel(const int* __restrict__ off, const int* __restrict__ csr,
                              const float* __restrict__ hws, const float* __restrict__ dinv,
                              const float* __restrict__ b, const int* __restrict__ batch,
                              float* __restrict__ hout, float* __restrict__ pooled,
                              float* __restrict__ cnt, int n) {
    int d = blockIdx.x * (blockDim.x >> 6) + (threadIdx.x >> 6);
    int lane = threadIdx.x & 63;
    if (d >= n) return;
    int beg = off[d], end = off[d + 1];
    float acc[16];
#pragma unroll
    for (int j = 0; j < 16; ++j) acc[j] = 0.f;

    for (int base = beg; base < end; base += 64) {
        int m = end - base; if (m > 64) m = 64;
        int myidx = (lane < m) ? csr[base + lane] : 0;
        int i = 0;
        for (; i + 16 <= m; i += 16) {
#pragma unroll
            for (int j = 0; j < 16; ++j) {
                int s = __builtin_amdgcn_readlane(myidx, i + j);  // SGPR index
                acc[j] += hws[(size_t)s * 64 + lane];             // saddr-form load
            }
        }
        // tail: wave-uniform branches (m uniform), static acc indices, no waste
#pragma unroll
        for (int j = 0; j < 15; ++j) {
            if (i + j < m) {
                int s = __builtin_amdgcn_readlane(myidx, i + j);
                acc[j] += hws[(size_t)s * 64 + lane];
            }
        }
    }
    float t0 = ((acc[0] + acc[1]) + (acc[2] + acc[3])) +
               ((acc[4] + acc[5]) + (acc[6] + acc[7]));
    float t1 = ((acc[8] + acc[9]) + (acc[10] + acc[11])) +
               ((acc[12] + acc[13]) + (acc[14] + acc[15]));
    float v = (t0 + t1 + hws[(size_t)d * 64 + lane]) * dinv[d] + b[lane];
    v = fmaxf(v, 0.f);
    if (POOL) {
        int g = batch[d];
        atomicAdd(&pooled[(size_t)g * 64 + lane], v);
        if (lane == 0) atomicAdd(&cnt[g], 1.0f);
    } else {
        hout[(size_t)d * 64 + lane] = v;
    }
}

// --- per-graph head: out[g] = dot(pooled[g]/max(cnt,1), Wfc) + bfc ---
__global__ void final_kernel(const float* __restrict__ pooled, const float* __restrict__ cnt,
                             const float* __restrict__ Wfc, const float* __restrict__ bfc,
                             float* __restrict__ out) {
    int g = blockIdx.x;
    int lane = threadIdx.x;  // block = 64 = 1 wave
    float c = fmaxf(cnt[g], 1.0f);
    float v = (pooled[(size_t)g * 64 + lane] / c) * Wfc[lane];
#pragma unroll
    for (int off = 32; off; off >>= 1) v += __shfl_down(v, off);
    if (lane == 0) out[g] = v + bfc[0];
}

extern "C" void kernel_launch(void* const* d_in, const int* in_sizes, int n_in,
                              void* d_out, int out_size, void* d_ws, size_t ws_size,
                              hipStream_t stream) {
    const float* x    = (const float*)d_in[0];
    const int*   ei   = (const int*)d_in[1];
    const int*   batch= (const int*)d_in[2];
    const float* W1   = (const float*)d_in[3];
    const float* b1   = (const float*)d_in[4];
    const float* W2   = (const float*)d_in[5];
    const float* b2   = (const float*)d_in[6];
    const float* Wfc  = (const float*)d_in[7];
    const float* bfc  = (const float*)d_in[8];
    float* out = (float*)d_out;

    const int n = in_sizes[0] / F_IN;   // 100000
    const int e = in_sizes[1] / 2;      // 3200000
    const int* srcp = ei;
    const int* dstp = ei + e;

    size_t nAl = ((size_t)n + 256) & ~(size_t)255;
    int*   deg     = (int*)d_ws;
    int*   off     = deg + nAl;
    int*   cursor  = off + nAl;
    int*   partial = cursor + nAl;
    float* dinv    = (float*)(partial + 256);
    int*   csr     = (int*)(dinv + nAl);
    size_t eAl     = ((size_t)e + 255) & ~(size_t)255;
    float* hws     = (float*)(csr + eAl);
    float* h1      = hws + (size_t)n * 64;
    float* pooled  = h1 + (size_t)n * 64;
    float* cnt     = pooled + (size_t)NUM_GRAPHS * 64;

    const int nb = (n + SCAN_CHUNK - 1) / SCAN_CHUNK;

    // 1. CSR build
    hipMemsetAsync(deg, 0, (size_t)n * sizeof(int), stream);
    hist_kernel<<<(e + 255) / 256, 256, 0, stream>>>(dstp, deg, e);
    scan_partial<<<nb, SCAN_BLK, 0, stream>>>(deg, partial, n);
    scan_spine<<<1, 64, 0, stream>>>(partial, nb, &off[n]);
    scan_final<<<nb, SCAN_BLK, 0, stream>>>(deg, partial, off, cursor, dinv, n);
    fill_kernel<<<(e + 255) / 256, 256, 0, stream>>>(srcp, dstp, cursor, csr, e);

    // 2. layer 1
    gemm_kernel<F_IN><<<(n + 3) / 4, 256, 0, stream>>>(x, W1, dinv, hws, n);
    gather_kernel<false><<<(n + 3) / 4, 256, 0, stream>>>(off, csr, hws, dinv, b1, batch,
                                                          h1, nullptr, nullptr, n);

    // 3. layer 2
    gemm_kernel<HDIM><<<(n + 3) / 4, 256, 0, stream>>>(h1, W2, dinv, hws, n);
    hipMemsetAsync(pooled, 0, ((size_t)NUM_GRAPHS * 64 + NUM_GRAPHS) * sizeof(float), stream);
    gather_kernel<true><<<(n + 3) / 4, 256, 0, stream>>>(off, csr, hws, dinv, b2, batch,
                                                         nullptr, pooled, cnt, n);

    // 4. head
    final_kernel<<<NUM_GRAPHS, 64, 0, stream>>>(pooled, cnt, Wfc, bfc, out);
}

// Round 14
// 1349.384 us; speedup vs baseline: 1.0839x; 1.0839x over previous
//
#include <hip/hip_runtime.h>

#define F_IN 128
#define HDIM 64
#define NUM_GRAPHS 256
#define SCAN_BLK 256
#define SCAN_CHUNK 2048   // 256 threads x 8 elems

// --- degree histogram (int): deg[dst] += 1 per edge ---
__global__ void hist_kernel(const int* __restrict__ dst, int* __restrict__ deg, int e) {
    int i = blockIdx.x * blockDim.x + threadIdx.x;
    if (i < e) atomicAdd(&deg[dst[i]], 1);
}

// --- scan pass A: per-block sums of deg over SCAN_CHUNK elems ---
__global__ void scan_partial(const int* __restrict__ deg, int* __restrict__ partial, int n) {
    __shared__ int lds[SCAN_BLK];
    int b = blockIdx.x, t = threadIdx.x;
    int base = b * SCAN_CHUNK + t * 8;
    int s = 0;
#pragma unroll
    for (int j = 0; j < 8; ++j) { int idx = base + j; if (idx < n) s += deg[idx]; }
    lds[t] = s; __syncthreads();
    for (int off = SCAN_BLK / 2; off; off >>= 1) {
        if (t < off) lds[t] += lds[t + off];
        __syncthreads();
    }
    if (t == 0) partial[b] = lds[0];
}

// --- scan pass B: serial exclusive scan of block sums (nb ~ 49) ---
__global__ void scan_spine(int* __restrict__ partial, int nb, int* __restrict__ off_end) {
    if (threadIdx.x == 0 && blockIdx.x == 0) {
        int run = 0;
        for (int i = 0; i < nb; ++i) { int v = partial[i]; partial[i] = run; run += v; }
        off_end[0] = run;
    }
}

// --- scan pass C: final exclusive scan; writes off[], cursor[], dinv[] ---
__global__ void scan_final(const int* __restrict__ deg, const int* __restrict__ partial,
                           int* __restrict__ off, int* __restrict__ cursor,
                           float* __restrict__ dinv, int n) {
    __shared__ int lds[SCAN_BLK];
    int b = blockIdx.x, t = threadIdx.x;
    int base = b * SCAN_CHUNK + t * 8;
    int v[8]; int s = 0;
#pragma unroll
    for (int j = 0; j < 8; ++j) { int idx = base + j; v[j] = (idx < n) ? deg[idx] : 0; s += v[j]; }
    lds[t] = s; __syncthreads();
    for (int o = 1; o < SCAN_BLK; o <<= 1) {
        int y = (t >= o) ? lds[t - o] : 0;
        __syncthreads();
        if (t >= o) lds[t] += y;
        __syncthreads();
    }
    int run = partial[b] + lds[t] - s;
#pragma unroll
    for (int j = 0; j < 8; ++j) {
        int idx = base + j;
        if (idx < n) {
            off[idx] = run; cursor[idx] = run;
            dinv[idx] = rsqrtf((float)v[j] + 1.0f);   // +1 self-loop
        }
        run += v[j];
    }
}

// --- CSR fill: csr[cursor[dst]++] = src ---
__global__ void fill_kernel(const int* __restrict__ src, const int* __restrict__ dst,
                            int* __restrict__ cursor, int* __restrict__ csr, int e) {
    int i = blockIdx.x * blockDim.x + threadIdx.x;
    if (i < e) {
        int pos = atomicAdd(&cursor[dst[i]], 1);
        csr[pos] = src[i];
    }
}

// --- small GEMM: out[n,64] = (A[n,K] @ W[K,64]) * dinv[row] ---
template<int K>
__global__ void gemm_kernel(const float* __restrict__ A, const float* __restrict__ W,
                            const float* __restrict__ dinv, float* __restrict__ out, int n) {
    __shared__ float Ws[K * 64];
    for (int i = threadIdx.x; i < K * 64; i += blockDim.x) Ws[i] = W[i];
    __syncthreads();
    int row  = blockIdx.x * (blockDim.x >> 6) + (threadIdx.x >> 6);
    int lane = threadIdx.x & 63;
    if (row >= n) return;
    const float4* ar = reinterpret_cast<const float4*>(A + (size_t)row * K);
    float acc = 0.f;
#pragma unroll
    for (int k4 = 0; k4 < K / 4; ++k4) {
        float4 av = ar[k4];
        acc = fmaf(av.x, Ws[(k4 * 4 + 0) * 64 + lane], acc);
        acc = fmaf(av.y, Ws[(k4 * 4 + 1) * 64 + lane], acc);
        acc = fmaf(av.z, Ws[(k4 * 4 + 2) * 64 + lane], acc);
        acc = fmaf(av.w, Ws[(k4 * 4 + 3) * 64 + lane], acc);
    }
    out[(size_t)row * 64 + lane] = acc * dinv[row];
}

// --- gather: TWO dst nodes per wave, lane = feature. R4's load shape
// (full-wave dword, one 256-B segment per instr, shfl-broadcast index)
// but 2 independent index streams -> up to 16 rows in flight per wave. ---
template<bool POOL>
__global__ void gather_kernel(const int* __restrict__ off, const int* __restrict__ csr,
                              const float* __restrict__ hws, const float* __restrict__ dinv,
                              const float* __restrict__ b, const int* __restrict__ batch,
                              float* __restrict__ hout, float* __restrict__ pooled,
                              float* __restrict__ cnt, int n) {
    int w = blockIdx.x * (blockDim.x >> 6) + (threadIdx.x >> 6);
    int lane = threadIdx.x & 63;
    int d0 = 2 * w, d1 = 2 * w + 1;
    if (d0 >= n) return;
    bool has1 = (d1 < n);
    int i0 = off[d0], e0 = off[d0 + 1];
    int i1 = has1 ? off[d1] : 0, e1 = has1 ? off[d1 + 1] : 0;
    int l8 = lane & 7;

    float acc0[8], acc1[8];
#pragma unroll
    for (int j = 0; j < 8; ++j) { acc0[j] = 0.f; acc1[j] = 0.f; }

    // interleaved main: both nodes have >=8 edges left -> 16 loads in flight
    while (i0 + 8 <= e0 && i1 + 8 <= e1) {
        int v0 = csr[i0 + l8];
        int v1 = csr[i1 + l8];
#pragma unroll
        for (int j = 0; j < 8; ++j) {
            int s0 = __shfl(v0, j);
            acc0[j] += hws[(size_t)s0 * 64 + lane];
            int s1 = __shfl(v1, j);
            acc1[j] += hws[(size_t)s1 * 64 + lane];
        }
        i0 += 8; i1 += 8;
    }
    // drain node0
    while (i0 + 8 <= e0) {
        int v0 = csr[i0 + l8];
#pragma unroll
        for (int j = 0; j < 8; ++j) {
            int s0 = __shfl(v0, j);
            acc0[j] += hws[(size_t)s0 * 64 + lane];
        }
        i0 += 8;
    }
    // drain node1
    while (i1 + 8 <= e1) {
        int v1 = csr[i1 + l8];
#pragma unroll
        for (int j = 0; j < 8; ++j) {
            int s1 = __shfl(v1, j);
            acc1[j] += hws[(size_t)s1 * 64 + lane];
        }
        i1 += 8;
    }
    // tails (<8), predicated, static acc indices
    int m0 = e0 - i0;
    if (m0 > 0) {
        int v0 = csr[(i0 + l8 < e0) ? (i0 + l8) : (e0 - 1)];
#pragma unroll
        for (int j = 0; j < 7; ++j) {
            int s0 = __shfl(v0, j);
            float f = hws[(size_t)s0 * 64 + lane];
            if (j < m0) acc0[j] += f;
        }
    }
    int m1 = e1 - i1;
    if (m1 > 0) {
        int v1 = csr[(i1 + l8 < e1) ? (i1 + l8) : (e1 - 1)];
#pragma unroll
        for (int j = 0; j < 7; ++j) {
            int s1 = __shfl(v1, j);
            float f = hws[(size_t)s1 * 64 + lane];
            if (j < m1) acc1[j] += f;
        }
    }

    float t0 = ((acc0[0] + acc0[1]) + (acc0[2] + acc0[3])) +
               ((acc0[4] + acc0[5]) + (acc0[6] + acc0[7]));
    float v = (t0 + hws[(size_t)d0 * 64 + lane]) * dinv[d0] + b[lane];
    v = fmaxf(v, 0.f);
    if (POOL) {
        int g = batch[d0];
        atomicAdd(&pooled[(size_t)g * 64 + lane], v);
        if (lane == 0) atomicAdd(&cnt[g], 1.0f);
    } else {
        hout[(size_t)d0 * 64 + lane] = v;
    }
    if (has1) {
        float t1 = ((acc1[0] + acc1[1]) + (acc1[2] + acc1[3])) +
                   ((acc1[4] + acc1[5]) + (acc1[6] + acc1[7]));
        float v1v = (t1 + hws[(size_t)d1 * 64 + lane]) * dinv[d1] + b[lane];
        v1v = fmaxf(v1v, 0.f);
        if (POOL) {
            int g = batch[d1];
            atomicAdd(&pooled[(size_t)g * 64 + lane], v1v);
            if (lane == 0) atomicAdd(&cnt[g], 1.0f);
        } else {
            hout[(size_t)d1 * 64 + lane] = v1v;
        }
    }
}

// --- per-graph head: out[g] = dot(pooled[g]/max(cnt,1), Wfc) + bfc ---
__global__ void final_kernel(const float* __restrict__ pooled, const float* __restrict__ cnt,
                             const float* __restrict__ Wfc, const float* __restrict__ bfc,
                             float* __restrict__ out) {
    int g = blockIdx.x;
    int lane = threadIdx.x;  // block = 64 = 1 wave
    float c = fmaxf(cnt[g], 1.0f);
    float v = (pooled[(size_t)g * 64 + lane] / c) * Wfc[lane];
#pragma unroll
    for (int off = 32; off; off >>= 1) v += __shfl_down(v, off);
    if (lane == 0) out[g] = v + bfc[0];
}

extern "C" void kernel_launch(void* const* d_in, const int* in_sizes, int n_in,
                              void* d_out, int out_size, void* d_ws, size_t ws_size,
                              hipStream_t stream) {
    const float* x    = (const float*)d_in[0];
    const int*   ei   = (const int*)d_in[1];
    const int*   batch= (const int*)d_in[2];
    const float* W1   = (const float*)d_in[3];
    const float* b1   = (const float*)d_in[4];
    const float* W2   = (const float*)d_in[5];
    const float* b2   = (const float*)d_in[6];
    const float* Wfc  = (const float*)d_in[7];
    const float* bfc  = (const float*)d_in[8];
    float* out = (float*)d_out;

    const int n = in_sizes[0] / F_IN;   // 100000
    const int e = in_sizes[1] / 2;      // 3200000
    const int* srcp = ei;
    const int* dstp = ei + e;

    size_t nAl = ((size_t)n + 256) & ~(size_t)255;
    int*   deg     = (int*)d_ws;
    int*   off     = deg + nAl;
    int*   cursor  = off + nAl;
    int*   partial = cursor + nAl;
    float* dinv    = (float*)(partial + 256);
    int*   csr     = (int*)(dinv + nAl);
    size_t eAl     = ((size_t)e + 255) & ~(size_t)255;
    float* hws     = (float*)(csr + eAl);
    float* h1      = hws + (size_t)n * 64;
    float* pooled  = h1 + (size_t)n * 64;
    float* cnt     = pooled + (size_t)NUM_GRAPHS * 64;

    const int nb = (n + SCAN_CHUNK - 1) / SCAN_CHUNK;
    const int nwave = (n + 1) / 2;                 // 2 nodes per wave
    const int gblocks = (nwave + 3) / 4;           // 4 waves per block

    // 1. CSR build
    hipMemsetAsync(deg, 0, (size_t)n * sizeof(int), stream);
    hist_kernel<<<(e + 255) / 256, 256, 0, stream>>>(dstp, deg, e);
    scan_partial<<<nb, SCAN_BLK, 0, stream>>>(deg, partial, n);
    scan_spine<<<1, 64, 0, stream>>>(partial, nb, &off[n]);
    scan_final<<<nb, SCAN_BLK, 0, stream>>>(deg, partial, off, cursor, dinv, n);
    fill_kernel<<<(e + 255) / 256, 256, 0, stream>>>(srcp, dstp, cursor, csr, e);

    // 2. layer 1
    gemm_kernel<F_IN><<<(n + 3) / 4, 256, 0, stream>>>(x, W1, dinv, hws, n);
    gather_kernel<false><<<gblocks, 256, 0, stream>>>(off, csr, hws, dinv, b1, batch,
                                                      h1, nullptr, nullptr, n);

    // 3. layer 2
    gemm_kernel<HDIM><<<(n + 3) / 4, 256, 0, stream>>>(h1, W2, dinv, hws, n);
    hipMemsetAsync(pooled, 0, ((size_t)NUM_GRAPHS * 64 + NUM_GRAPHS) * sizeof(float), stream);
    gather_kernel<true><<<gblocks, 256, 0, stream>>>(off, csr, hws, dinv, b2, batch,
                                                     nullptr, pooled, cnt, n);

    // 4. head
    final_kernel<<<NUM_GRAPHS, 64, 0, stream>>>(pooled, cnt, Wfc, bfc, out);
}

// Round 15
// 1295.381 us; speedup vs baseline: 1.1291x; 1.0417x over previous
//
#include <hip/hip_runtime.h>

#define F_IN 128
#define HDIM 64
#define NUM_GRAPHS 256
#define SCAN_BLK 256
#define SCAN_CHUNK 2048   // 256 threads x 8 elems

// --- degree histogram (int): deg[dst] += 1 per edge ---
__global__ void hist_kernel(const int* __restrict__ dst, int* __restrict__ deg, int e) {
    int i = blockIdx.x * blockDim.x + threadIdx.x;
    if (i < e) atomicAdd(&deg[dst[i]], 1);
}

// --- scan pass A: per-block sums of deg over SCAN_CHUNK elems ---
__global__ void scan_partial(const int* __restrict__ deg, int* __restrict__ partial, int n) {
    __shared__ int lds[SCAN_BLK];
    int b = blockIdx.x, t = threadIdx.x;
    int base = b * SCAN_CHUNK + t * 8;
    int s = 0;
#pragma unroll
    for (int j = 0; j < 8; ++j) { int idx = base + j; if (idx < n) s += deg[idx]; }
    lds[t] = s; __syncthreads();
    for (int off = SCAN_BLK / 2; off; off >>= 1) {
        if (t < off) lds[t] += lds[t + off];
        __syncthreads();
    }
    if (t == 0) partial[b] = lds[0];
}

// --- scan pass B: serial exclusive scan of block sums (nb ~ 49) ---
__global__ void scan_spine(int* __restrict__ partial, int nb, int* __restrict__ off_end) {
    if (threadIdx.x == 0 && blockIdx.x == 0) {
        int run = 0;
        for (int i = 0; i < nb; ++i) { int v = partial[i]; partial[i] = run; run += v; }
        off_end[0] = run;
    }
}

// --- scan pass C: final exclusive scan; writes off[], cursor[], dinv[] ---
__global__ void scan_final(const int* __restrict__ deg, const int* __restrict__ partial,
                           int* __restrict__ off, int* __restrict__ cursor,
                           float* __restrict__ dinv, int n) {
    __shared__ int lds[SCAN_BLK];
    int b = blockIdx.x, t = threadIdx.x;
    int base = b * SCAN_CHUNK + t * 8;
    int v[8]; int s = 0;
#pragma unroll
    for (int j = 0; j < 8; ++j) { int idx = base + j; v[j] = (idx < n) ? deg[idx] : 0; s += v[j]; }
    lds[t] = s; __syncthreads();
    for (int o = 1; o < SCAN_BLK; o <<= 1) {
        int y = (t >= o) ? lds[t - o] : 0;
        __syncthreads();
        if (t >= o) lds[t] += y;
        __syncthreads();
    }
    int run = partial[b] + lds[t] - s;
#pragma unroll
    for (int j = 0; j < 8; ++j) {
        int idx = base + j;
        if (idx < n) {
            off[idx] = run; cursor[idx] = run;
            dinv[idx] = rsqrtf((float)v[j] + 1.0f);   // +1 self-loop
        }
        run += v[j];
    }
}

// --- CSR fill: csr[cursor[dst]++] = src ---
__global__ void fill_kernel(const int* __restrict__ src, const int* __restrict__ dst,
                            int* __restrict__ cursor, int* __restrict__ csr, int e) {
    int i = blockIdx.x * blockDim.x + threadIdx.x;
    if (i < e) {
        int pos = atomicAdd(&cursor[dst[i]], 1);
        csr[pos] = src[i];
    }
}

// --- small GEMM: out[n,64] = (A[n,K] @ W[K,64]) * dinv[row] ---
template<int K>
__global__ void gemm_kernel(const float* __restrict__ A, const float* __restrict__ W,
                            const float* __restrict__ dinv, float* __restrict__ out, int n) {
    __shared__ float Ws[K * 64];
    for (int i = threadIdx.x; i < K * 64; i += blockDim.x) Ws[i] = W[i];
    __syncthreads();
    int row  = blockIdx.x * (blockDim.x >> 6) + (threadIdx.x >> 6);
    int lane = threadIdx.x & 63;
    if (row >= n) return;
    const float4* ar = reinterpret_cast<const float4*>(A + (size_t)row * K);
    float acc = 0.f;
#pragma unroll
    for (int k4 = 0; k4 < K / 4; ++k4) {
        float4 av = ar[k4];
        acc = fmaf(av.x, Ws[(k4 * 4 + 0) * 64 + lane], acc);
        acc = fmaf(av.y, Ws[(k4 * 4 + 1) * 64 + lane], acc);
        acc = fmaf(av.z, Ws[(k4 * 4 + 2) * 64 + lane], acc);
        acc = fmaf(av.w, Ws[(k4 * 4 + 3) * 64 + lane], acc);
    }
    out[(size_t)row * 64 + lane] = acc * dinv[row];
}

// --- gather aggregation: one wave per dst node, lane = feature ---
// R4 structure (best measured). NT: row loads bypass L1 via nontemporal.
template<bool POOL, bool NT>
__global__ void gather_kernel(const int* __restrict__ off, const int* __restrict__ csr,
                              const float* __restrict__ hws, const float* __restrict__ dinv,
                              const float* __restrict__ b, const int* __restrict__ batch,
                              float* __restrict__ hout, float* __restrict__ pooled,
                              float* __restrict__ cnt, int n) {
    int d = blockIdx.x * (blockDim.x >> 6) + (threadIdx.x >> 6);
    int lane = threadIdx.x & 63;
    if (d >= n) return;
    int beg = off[d], end = off[d + 1];
    float acc[8];
#pragma unroll
    for (int j = 0; j < 8; ++j) acc[j] = 0.f;

    for (int base = beg; base < end; base += 64) {
        int m = end - base; if (m > 64) m = 64;
        int myidx = (lane < m) ? csr[base + lane] : 0;
        int i = 0;
        for (; i + 8 <= m; i += 8) {
#pragma unroll
            for (int j = 0; j < 8; ++j) {
                int s = __shfl(myidx, i + j);
                const float* p = &hws[(size_t)s * 64 + lane];
                acc[j] += NT ? __builtin_nontemporal_load(p) : *p;
            }
        }
        for (; i < m; ++i) {
            int s = __shfl(myidx, i);
            const float* p = &hws[(size_t)s * 64 + lane];
            acc[i & 7] += NT ? __builtin_nontemporal_load(p) : *p;
        }
    }
    float tot = ((acc[0] + acc[1]) + (acc[2] + acc[3])) +
                ((acc[4] + acc[5]) + (acc[6] + acc[7]));
    float v = (tot + hws[(size_t)d * 64 + lane]) * dinv[d] + b[lane];
    v = fmaxf(v, 0.f);
    if (POOL) {
        int g = batch[d];
        atomicAdd(&pooled[(size_t)g * 64 + lane], v);
        if (lane == 0) atomicAdd(&cnt[g], 1.0f);
    } else {
        hout[(size_t)d * 64 + lane] = v;
    }
}

// --- per-graph head: out[g] = dot(pooled[g]/max(cnt,1), Wfc) + bfc ---
__global__ void final_kernel(const float* __restrict__ pooled, const float* __restrict__ cnt,
                             const float* __restrict__ Wfc, const float* __restrict__ bfc,
                             float* __restrict__ out) {
    int g = blockIdx.x;
    int lane = threadIdx.x;  // block = 64 = 1 wave
    float c = fmaxf(cnt[g], 1.0f);
    float v = (pooled[(size_t)g * 64 + lane] / c) * Wfc[lane];
#pragma unroll
    for (int off = 32; off; off >>= 1) v += __shfl_down(v, off);
    if (lane == 0) out[g] = v + bfc[0];
}

extern "C" void kernel_launch(void* const* d_in, const int* in_sizes, int n_in,
                              void* d_out, int out_size, void* d_ws, size_t ws_size,
                              hipStream_t stream) {
    const float* x    = (const float*)d_in[0];
    const int*   ei   = (const int*)d_in[1];
    const int*   batch= (const int*)d_in[2];
    const float* W1   = (const float*)d_in[3];
    const float* b1   = (const float*)d_in[4];
    const float* W2   = (const float*)d_in[5];
    const float* b2   = (const float*)d_in[6];
    const float* Wfc  = (const float*)d_in[7];
    const float* bfc  = (const float*)d_in[8];
    float* out = (float*)d_out;

    const int n = in_sizes[0] / F_IN;   // 100000
    const int e = in_sizes[1] / 2;      // 3200000
    const int* srcp = ei;
    const int* dstp = ei + e;

    size_t nAl = ((size_t)n + 256) & ~(size_t)255;
    int*   deg     = (int*)d_ws;
    int*   off     = deg + nAl;
    int*   cursor  = off + nAl;
    int*   partial = cursor + nAl;
    float* dinv    = (float*)(partial + 256);
    int*   csr     = (int*)(dinv + nAl);
    size_t eAl     = ((size_t)e + 255) & ~(size_t)255;
    float* hws     = (float*)(csr + eAl);
    float* h1      = hws + (size_t)n * 64;
    float* pooled  = h1 + (size_t)n * 64;
    float* cnt     = pooled + (size_t)NUM_GRAPHS * 64;

    const int nb = (n + SCAN_CHUNK - 1) / SCAN_CHUNK;

    // 1. CSR build
    hipMemsetAsync(deg, 0, (size_t)n * sizeof(int), stream);
    hist_kernel<<<(e + 255) / 256, 256, 0, stream>>>(dstp, deg, e);
    scan_partial<<<nb, SCAN_BLK, 0, stream>>>(deg, partial, n);
    scan_spine<<<1, 64, 0, stream>>>(partial, nb, &off[n]);
    scan_final<<<nb, SCAN_BLK, 0, stream>>>(deg, partial, off, cursor, dinv, n);
    fill_kernel<<<(e + 255) / 256, 256, 0, stream>>>(srcp, dstp, cursor, csr, e);

    // 2. layer 1 — NT (L1-bypass) row loads: the A-arm of the experiment
    gemm_kernel<F_IN><<<(n + 3) / 4, 256, 0, stream>>>(x, W1, dinv, hws, n);
    gather_kernel<false, true><<<(n + 3) / 4, 256, 0, stream>>>(off, csr, hws, dinv, b1, batch,
                                                                h1, nullptr, nullptr, n);

    // 3. layer 2 — normal loads: the B-arm (control)
    gemm_kernel<HDIM><<<(n + 3) / 4, 256, 0, stream>>>(h1, W2, dinv, hws, n);
    hipMemsetAsync(pooled, 0, ((size_t)NUM_GRAPHS * 64 + NUM_GRAPHS) * sizeof(float), stream);
    gather_kernel<true, false><<<(n + 3) / 4, 256, 0, stream>>>(off, csr, hws, dinv, b2, batch,
                                                                nullptr, pooled, cnt, n);

    // 4. head
    final_kernel<<<NUM_GRAPHS, 64, 0, stream>>>(pooled, cnt, Wfc, bfc, out);
}